// Round 4
// baseline (143.290 us; speedup 1.0000x reference)
//
#include <hip/hip_runtime.h>
#include <math.h>

#define B_ 4
#define S_ 2048
#define D_ 512
#define H_ 8
#define DH_ 64
#define BH_ (B_*H_)
#define SCALE 0.1803368801111243f   // log2(e)/sqrt(64)

typedef __attribute__((ext_vector_type(4)))  float f32x4;
typedef __attribute__((ext_vector_type(16))) float f32x16;
typedef __attribute__((ext_vector_type(8)))  short bf16x8;

__device__ inline uint rnepk(float a, float b) {
    uint ua = __builtin_bit_cast(uint, a), ub = __builtin_bit_cast(uint, b);
    ua += 0x7FFFu + ((ua >> 16) & 1u);
    ub += 0x7FFFu + ((ub >> 16) & 1u);
    return (ua >> 16) | (ub & 0xFFFF0000u);
}
__device__ inline uint truncpk(float lo, float hi) {   // 1 v_perm_b32
    return __builtin_amdgcn_perm(__builtin_bit_cast(uint, hi),
                                 __builtin_bit_cast(uint, lo), 0x07060302u);
}
__device__ inline f32x16 zero16() {
    f32x16 z;
    #pragma unroll
    for (int i = 0; i < 16; ++i) z[i] = 0.f;
    return z;
}

// ---------------------------------------------------------------------------
// Kernel 1: QKV projection, 32x32x16 MFMA. grid (BH_, S_/128), block 256.
// Wave w owns 32 s-rows. W staged once per 128 rows. Q/K: C=[e][s] (A=W,B=x),
// V: C=[s][e] (A=x,B=Wv — same fragments, swapped operands) -> writes Vt[e][s].
// All outputs bounced through per-wave LDS for fully-coalesced b128 stores.
// SCALE folded into Q. __launch_bounds__(256,2): no spills (~100 VGPR).
// ---------------------------------------------------------------------------
__global__ __launch_bounds__(256, 2)
void qkv_mfma(const float* __restrict__ x,
              const float* __restrict__ Wq, const float* __restrict__ bq,
              const float* __restrict__ Wk, const float* __restrict__ bk,
              const float* __restrict__ Wv, const float* __restrict__ bv,
              ushort* __restrict__ Qb, ushort* __restrict__ Kb,
              ushort* __restrict__ Vtg)
{
    const int bh = blockIdx.x, b = bh >> 3, h = bh & 7;
    const int s0 = blockIdx.y * 128;
    const int tid = threadIdx.x;
    const int w = tid >> 6, lane = tid & 63, l31 = lane & 31, l5 = lane >> 5;

    __shared__ __align__(16) ushort xs[128 * 64];     // [s][d] bf16 swizzled, 16 KB
    __shared__ __align__(16) ushort wl[3][64 * 64];   // [e][d] bf16 swizzled, 24 KB
    __shared__ __align__(16) ushort bnc[4][2560];     // per-wave bounce, 20 KB

    // ---- stage x: thread -> (row, half of 32 floats) ----
    {
        const int row = tid >> 1, half = tid & 1;
        const float* xr = x + ((size_t)(b * S_ + s0 + row)) * D_ + h * DH_ + half * 32;
        ushort* dst = xs + row * 64;
        #pragma unroll
        for (int i = 0; i < 2; ++i) {
            float4 f0 = *(const float4*)(xr + i * 16);
            float4 f1 = *(const float4*)(xr + i * 16 + 4);
            float4 f2 = *(const float4*)(xr + i * 16 + 8);
            float4 f3 = *(const float4*)(xr + i * 16 + 12);
            uint4 c0, c1;
            c0.x = rnepk(f0.x, f0.y); c0.y = rnepk(f0.z, f0.w);
            c0.z = rnepk(f1.x, f1.y); c0.w = rnepk(f1.z, f1.w);
            c1.x = rnepk(f2.x, f2.y); c1.y = rnepk(f2.z, f2.w);
            c1.z = rnepk(f3.x, f3.y); c1.w = rnepk(f3.z, f3.w);
            const int ch0 = half * 4 + i * 2;
            *(uint4*)(dst + ((ch0 ^ (row & 7)) * 8)) = c0;
            *(uint4*)(dst + (((ch0 + 1) ^ (row & 7)) * 8)) = c1;
        }
    }
    // ---- stage Wq/Wk/Wv ----
    {
        const float* Wm[3] = {Wq, Wk, Wv};
        #pragma unroll
        for (int it = 0; it < 6; ++it) {
            const int mat = it >> 1;
            const int e = (it & 1) * 32 + (tid >> 3), ch = tid & 7;
            const float* p = Wm[mat] + h * DH_ * DH_ + e * DH_ + ch * 8;
            float4 a = *(const float4*)(p);
            float4 c = *(const float4*)(p + 4);
            uint4 u;
            u.x = rnepk(a.x, a.y); u.y = rnepk(a.z, a.w);
            u.z = rnepk(c.x, c.y); u.w = rnepk(c.z, c.w);
            *(uint4*)(&wl[mat][e * 64 + ((ch ^ (e & 7)) * 8)]) = u;
        }
    }
    __syncthreads();

    // x fragments (A-role and B-role identical layout): row = w*32 + l31
    const int srow = w * 32 + l31;
    bf16x8 xf[4];
    #pragma unroll
    for (int st = 0; st < 4; ++st)
        xf[st] = *(const bf16x8*)(xs + srow * 64 + (((st * 2 + l5) ^ (srow & 7)) * 8));

    ushort* mybnc = &bnc[w][0];

    // ---- Q and K: C[e][s], col = s = l31, rows e = (reg&3)+8rg+4l5 ----
    #pragma unroll
    for (int mat = 0; mat < 2; ++mat) {
        const float* bias = mat ? bk : bq;
        f32x16 acc[2];
        #pragma unroll
        for (int et = 0; et < 2; ++et) {
            acc[et] = zero16();
            const int e = et * 32 + l31;
            #pragma unroll
            for (int st = 0; st < 4; ++st) {
                bf16x8 wf = *(const bf16x8*)(&wl[mat][e * 64 + (((st * 2 + l5) ^ (e & 7)) * 8)]);
                acc[et] = __builtin_amdgcn_mfma_f32_32x32x16_bf16(wf, xf[st], acc[et], 0, 0, 0);
            }
        }
        #pragma unroll
        for (int et = 0; et < 2; ++et)
            #pragma unroll
            for (int rg = 0; rg < 4; ++rg) {
                float4 b4 = *(const float4*)(bias + h * DH_ + et * 32 + rg * 8 + l5 * 4);
                float v0 = acc[et][rg * 4 + 0] + b4.x;
                float v1 = acc[et][rg * 4 + 1] + b4.y;
                float v2 = acc[et][rg * 4 + 2] + b4.z;
                float v3 = acc[et][rg * 4 + 3] + b4.w;
                if (mat == 0) { v0 *= SCALE; v1 *= SCALE; v2 *= SCALE; v3 *= SCALE; }
                uint2 pk;
                pk.x = rnepk(v0, v1); pk.y = rnepk(v2, v3);
                *(uint2*)(mybnc + l31 * 72 + et * 32 + rg * 8 + l5 * 4) = pk;  // [s][e]
            }
        ushort* Og = mat ? Kb : Qb;
        #pragma unroll
        for (int i = 0; i < 4; ++i) {                    // 32 rows x 8 chunks
            const int slot = lane + 64 * i;
            const int r = slot >> 3, c = slot & 7;
            uint4 v = *(const uint4*)(mybnc + r * 72 + c * 8);
            *(uint4*)(Og + ((size_t)(bh * S_ + s0 + w * 32 + r)) * DH_ + c * 8) = v;
        }
    }

    // ---- V: C[s][e], col = e = et*32+l31, rows s = (reg&3)+8rg+4l5 ----
    {
        f32x16 acc[2];
        #pragma unroll
        for (int et = 0; et < 2; ++et) {
            acc[et] = zero16();
            const int e = et * 32 + l31;
            #pragma unroll
            for (int st = 0; st < 4; ++st) {
                bf16x8 wf = *(const bf16x8*)(&wl[2][e * 64 + (((st * 2 + l5) ^ (e & 7)) * 8)]);
                acc[et] = __builtin_amdgcn_mfma_f32_32x32x16_bf16(xf[st], wf, acc[et], 0, 0, 0);
            }
        }
        const float bvv0 = bv[h * DH_ + l31], bvv1 = bv[h * DH_ + 32 + l31];
        #pragma unroll
        for (int et = 0; et < 2; ++et) {
            const float bb = et ? bvv1 : bvv0;
            #pragma unroll
            for (int rg = 0; rg < 4; ++rg) {
                float v0 = acc[et][rg * 4 + 0] + bb;
                float v1 = acc[et][rg * 4 + 1] + bb;
                float v2 = acc[et][rg * 4 + 2] + bb;
                float v3 = acc[et][rg * 4 + 3] + bb;
                uint2 pk;
                pk.x = rnepk(v0, v1); pk.y = rnepk(v2, v3);
                // bncV[e][s]: stride 40 ushorts (80 B, 16B-mult)
                *(uint2*)(mybnc + (et * 32 + l31) * 40 + rg * 8 + l5 * 4) = pk;
            }
        }
        #pragma unroll
        for (int i = 0; i < 4; ++i) {                    // 64 rows x 4 chunks
            const int slot = lane + 64 * i;
            const int r = slot >> 2, c = slot & 3;       // r = e, c = 16B chunk of s
            uint4 v = *(const uint4*)(mybnc + r * 40 + c * 8);
            *(uint4*)(Vtg + ((size_t)(bh * DH_ + r)) * S_ + s0 + w * 32 + c * 8) = v;
        }
    }
}

// ---------------------------------------------------------------------------
// Kernel 2: flash attention, 32x32x16 MFMA, 64 q-rows/wave, S^T orientation.
// grid = 256 blocks (bh = blk&31 -> same-bh blocks share an XCD for K/V L2
// locality), block = 4 waves = 256 q-rows. Double-buffered K/V staging, one
// barrier per kt. P round-trips per-wave LDS (stride 72 ushort = 144 B,
// 16B-mult). O^T normalized then bounced through LDS for coalesced stores.
// ---------------------------------------------------------------------------
__global__ __launch_bounds__(256, 1)
void flash_mfma(const ushort* __restrict__ Qb, const ushort* __restrict__ Kb,
                const ushort* __restrict__ Vtg, float* __restrict__ out)
{
    const int blk = blockIdx.x;
    const int bh = blk & 31, qblk = blk >> 5;
    const int b = bh >> 3, h = bh & 7;
    const int tid = threadIdx.x;
    const int w = tid >> 6, lane = tid & 63, l31 = lane & 31, l5 = lane >> 5;

    // [0,8K): Ks buf0/1 | [8K,16K): Vs buf0/1 | [16K,34.8K): P per-wave
    __shared__ __align__(16) ushort lds_u[16384 + 4 * 64 * 72];   // 69632 B
    ushort* Pw = lds_u + 16384 + w * (64 * 72);

    // ---- Q B-frags (held all kernel) ----
    const int q0 = qblk * 256 + w * 64;
    bf16x8 qf[2][4];
    #pragma unroll
    for (int qt = 0; qt < 2; ++qt)
        #pragma unroll
        for (int st = 0; st < 4; ++st)
            qf[qt][st] = *(const bf16x8*)(Qb + ((size_t)(bh * S_ + q0 + qt * 32 + l31)) * DH_
                                          + st * 16 + l5 * 8);

    f32x16 O[2][2];   // [dht][qt]
    #pragma unroll
    for (int i = 0; i < 2; ++i)
        #pragma unroll
        for (int j = 0; j < 2; ++j) O[i][j] = zero16();
    float lsum[2] = {0.f, 0.f};

    const ushort* kg = Kb + (size_t)bh * S_ * DH_;
    const ushort* vg = Vtg + (size_t)bh * DH_ * S_;
    const int sr0 = tid >> 3, sc0 = tid & 7;             // slot 0
    const int sr1 = (tid + 256) >> 3, sc1 = tid & 7;     // slot 1

    // ---- prologue: stage kt=0 into buffer 0 ----
    uint4 kv0, kv1, vv0, vv1;
    kv0 = *(const uint4*)(kg + (size_t)sr0 * DH_ + sc0 * 8);
    kv1 = *(const uint4*)(kg + (size_t)sr1 * DH_ + sc1 * 8);
    vv0 = *(const uint4*)(vg + (size_t)sr0 * S_ + sc0 * 8);
    vv1 = *(const uint4*)(vg + (size_t)sr1 * S_ + sc1 * 8);
    *(uint4*)(lds_u + sr0 * 64 + ((sc0 ^ (sr0 & 7)) * 8)) = kv0;
    *(uint4*)(lds_u + sr1 * 64 + ((sc1 ^ (sr1 & 7)) * 8)) = kv1;
    *(uint4*)(lds_u + 8192 + sr0 * 64 + ((sc0 ^ (sr0 & 7)) * 8)) = vv0;
    *(uint4*)(lds_u + 8192 + sr1 * 64 + ((sc1 ^ (sr1 & 7)) * 8)) = vv1;

    for (int kt = 0; kt < 32; ++kt) {
        __syncthreads();
        const int cur = kt & 1, nxt = cur ^ 1;
        if (kt < 31) {   // issue next-tile global loads; consumed after compute
            const size_t ko = (size_t)(kt + 1) * 64 * DH_;
            const int vo = (kt + 1) * 64;
            kv0 = *(const uint4*)(kg + ko + (size_t)sr0 * DH_ + sc0 * 8);
            kv1 = *(const uint4*)(kg + ko + (size_t)sr1 * DH_ + sc1 * 8);
            vv0 = *(const uint4*)(vg + (size_t)sr0 * S_ + vo + sc0 * 8);
            vv1 = *(const uint4*)(vg + (size_t)sr1 * S_ + vo + sc1 * 8);
        }
        const ushort* ksb = lds_u + cur * 4096;
        const ushort* vsb = lds_u + 8192 + cur * 4096;

        // ---- S^T = K·Q^T: 4 C-tiles [kt32][qt]; exp+pack+P-store per tile ----
        #pragma unroll
        for (int kt32 = 0; kt32 < 2; ++kt32) {
            const int key = kt32 * 32 + l31;
            bf16x8 kf[4];
            #pragma unroll
            for (int st = 0; st < 4; ++st)
                kf[st] = *(const bf16x8*)(ksb + key * 64 + (((st * 2 + l5) ^ (key & 7)) * 8));
            #pragma unroll
            for (int qt = 0; qt < 2; ++qt) {
                f32x16 sc = zero16();
                #pragma unroll
                for (int st = 0; st < 4; ++st)
                    sc = __builtin_amdgcn_mfma_f32_32x32x16_bf16(kf[st], qf[qt][st], sc, 0, 0, 0);
                float ls = 0.f;
                #pragma unroll
                for (int rg = 0; rg < 4; ++rg) {
                    float p0 = __builtin_amdgcn_exp2f(sc[rg * 4 + 0]);
                    float p1 = __builtin_amdgcn_exp2f(sc[rg * 4 + 1]);
                    float p2 = __builtin_amdgcn_exp2f(sc[rg * 4 + 2]);
                    float p3 = __builtin_amdgcn_exp2f(sc[rg * 4 + 3]);
                    ls += (p0 + p1) + (p2 + p3);
                    uint2 pk;
                    pk.x = truncpk(p0, p1); pk.y = truncpk(p2, p3);
                    *(uint2*)(Pw + (qt * 32 + l31) * 72 + kt32 * 32 + rg * 8 + l5 * 4) = pk;
                }
                lsum[qt] += ls;
            }
        }

        // ---- PV: O^T[dht][qt] += Vt·P^T ----
        bf16x8 pf[2][4];
        #pragma unroll
        for (int qt = 0; qt < 2; ++qt)
            #pragma unroll
            for (int st = 0; st < 4; ++st)
                pf[qt][st] = *(const bf16x8*)(Pw + (qt * 32 + l31) * 72 + st * 16 + l5 * 8);
        #pragma unroll
        for (int dht = 0; dht < 2; ++dht) {
            const int dh = dht * 32 + l31;
            bf16x8 vf[4];
            #pragma unroll
            for (int st = 0; st < 4; ++st)
                vf[st] = *(const bf16x8*)(vsb + dh * 64 + (((st * 2 + l5) ^ (dh & 7)) * 8));
            #pragma unroll
            for (int qt = 0; qt < 2; ++qt)
                #pragma unroll
                for (int st = 0; st < 4; ++st)
                    O[dht][qt] = __builtin_amdgcn_mfma_f32_32x32x16_bf16(vf[st], pf[qt][st],
                                                                          O[dht][qt], 0, 0, 0);
        }

        // ---- write staged regs -> next buffer ----
        if (kt < 31) {
            ushort* kn = lds_u + nxt * 4096;
            ushort* vn = lds_u + 8192 + nxt * 4096;
            *(uint4*)(kn + sr0 * 64 + ((sc0 ^ (sr0 & 7)) * 8)) = kv0;
            *(uint4*)(kn + sr1 * 64 + ((sc1 ^ (sr1 & 7)) * 8)) = kv1;
            *(uint4*)(vn + sr0 * 64 + ((sc0 ^ (sr0 & 7)) * 8)) = vv0;
            *(uint4*)(vn + sr1 * 64 + ((sc1 ^ (sr1 & 7)) * 8)) = vv1;
        }
    }

    // ---- finalize: l across l5 halves, normalize, bounce, coalesced store ----
    #pragma unroll
    for (int qt = 0; qt < 2; ++qt) {
        float l = lsum[qt] + __shfl_xor(lsum[qt], 32);
        lsum[qt] = 1.0f / l;
    }
    #pragma unroll
    for (int dht = 0; dht < 2; ++dht)
        #pragma unroll
        for (int qt = 0; qt < 2; ++qt)
            #pragma unroll
            for (int i = 0; i < 16; ++i) O[dht][qt][i] *= lsum[qt];

    __syncthreads();   // all waves done with Ks/Vs/P before overlay
    float* ob = (float*)lds_u + w * (64 * 68);   // per-wave [64 q][68] fp32
    #pragma unroll
    for (int dht = 0; dht < 2; ++dht)
        #pragma unroll
        for (int qt = 0; qt < 2; ++qt)
            #pragma unroll
            for (int rg = 0; rg < 4; ++rg) {
                f32x4 v4;
                v4[0] = O[dht][qt][rg * 4 + 0];
                v4[1] = O[dht][qt][rg * 4 + 1];
                v4[2] = O[dht][qt][rg * 4 + 2];
                v4[3] = O[dht][qt][rg * 4 + 3];
                *(f32x4*)(ob + (qt * 32 + l31) * 68 + dht * 32 + rg * 8 + l5 * 4) = v4;
            }
    #pragma unroll
    for (int i = 0; i < 16; ++i) {               // 64 rows x 16 chunks of 16 B
        const int slot = lane + 64 * i;
        const int r = slot >> 4, c = slot & 15;
        f32x4 v = *(const f32x4*)(ob + r * 68 + c * 4);
        *(f32x4*)(out + ((size_t)(b * S_ + q0 + r)) * D_ + h * DH_ + c * 4) = v;
    }
}

extern "C" void kernel_launch(void* const* d_in, const int* in_sizes, int n_in,
                              void* d_out, int out_size, void* d_ws, size_t ws_size,
                              hipStream_t stream) {
    const float* x  = (const float*)d_in[0];
    const float* Wq = (const float*)d_in[1];
    const float* bq = (const float*)d_in[2];
    const float* Wk = (const float*)d_in[3];
    const float* bk = (const float*)d_in[4];
    const float* Wv = (const float*)d_in[5];
    const float* bv = (const float*)d_in[6];
    float* outp = (float*)d_out;

    ushort* Qb  = (ushort*)d_ws;                       // [BH][S][DH] bf16, 8 MB
    ushort* Kb  = Qb + (size_t)BH_ * S_ * DH_;         // 8 MB
    ushort* Vtg = Kb + (size_t)BH_ * S_ * DH_;         // [BH][DH][S] bf16, 8 MB

    qkv_mfma<<<dim3(BH_, S_ / 128), 256, 0, stream>>>(x, Wq, bq, Wk, bk, Wv, bv,
                                                      Qb, Kb, Vtg);
    flash_mfma<<<dim3(BH_ * 8), 256, 0, stream>>>(Qb, Kb, Vtg, outp);
}

// Round 5
// 133.330 us; speedup vs baseline: 1.0747x; 1.0747x over previous
//
#include <hip/hip_runtime.h>
#include <math.h>

#define B_ 4
#define S_ 2048
#define D_ 512
#define H_ 8
#define DH_ 64
#define BH_ (B_*H_)
#define SCALE 0.1803368801111243f   // log2(e)/sqrt(64)

typedef __attribute__((ext_vector_type(4)))  float f32x4;
typedef __attribute__((ext_vector_type(16))) float f32x16;
typedef __attribute__((ext_vector_type(8)))  short bf16x8;
typedef __attribute__((ext_vector_type(4)))  uint  u32x4;

__device__ inline uint rnepk(float a, float b) {
    uint ua = __builtin_bit_cast(uint, a), ub = __builtin_bit_cast(uint, b);
    ua += 0x7FFFu + ((ua >> 16) & 1u);
    ub += 0x7FFFu + ((ub >> 16) & 1u);
    return (ua >> 16) | (ub & 0xFFFF0000u);
}
__device__ inline uint truncpk(float lo, float hi) {   // 1 v_perm_b32
    return __builtin_amdgcn_perm(__builtin_bit_cast(uint, hi),
                                 __builtin_bit_cast(uint, lo), 0x07060302u);
}
__device__ inline f32x16 zero16() {
    f32x16 z;
    #pragma unroll
    for (int i = 0; i < 16; ++i) z[i] = 0.f;
    return z;
}

// ---------------------------------------------------------------------------
// Kernel 1: QKV projection, 32x32x16 MFMA (unchanged from R4).
// ---------------------------------------------------------------------------
__global__ __launch_bounds__(256, 2)
void qkv_mfma(const float* __restrict__ x,
              const float* __restrict__ Wq, const float* __restrict__ bq,
              const float* __restrict__ Wk, const float* __restrict__ bk,
              const float* __restrict__ Wv, const float* __restrict__ bv,
              ushort* __restrict__ Qb, ushort* __restrict__ Kb,
              ushort* __restrict__ Vtg)
{
    const int bh = blockIdx.x, b = bh >> 3, h = bh & 7;
    const int s0 = blockIdx.y * 128;
    const int tid = threadIdx.x;
    const int w = tid >> 6, lane = tid & 63, l31 = lane & 31, l5 = lane >> 5;

    __shared__ __align__(16) ushort xs[128 * 64];
    __shared__ __align__(16) ushort wl[3][64 * 64];
    __shared__ __align__(16) ushort bnc[4][2560];

    {
        const int row = tid >> 1, half = tid & 1;
        const float* xr = x + ((size_t)(b * S_ + s0 + row)) * D_ + h * DH_ + half * 32;
        ushort* dst = xs + row * 64;
        #pragma unroll
        for (int i = 0; i < 2; ++i) {
            float4 f0 = *(const float4*)(xr + i * 16);
            float4 f1 = *(const float4*)(xr + i * 16 + 4);
            float4 f2 = *(const float4*)(xr + i * 16 + 8);
            float4 f3 = *(const float4*)(xr + i * 16 + 12);
            uint4 c0, c1;
            c0.x = rnepk(f0.x, f0.y); c0.y = rnepk(f0.z, f0.w);
            c0.z = rnepk(f1.x, f1.y); c0.w = rnepk(f1.z, f1.w);
            c1.x = rnepk(f2.x, f2.y); c1.y = rnepk(f2.z, f2.w);
            c1.z = rnepk(f3.x, f3.y); c1.w = rnepk(f3.z, f3.w);
            const int ch0 = half * 4 + i * 2;
            *(uint4*)(dst + ((ch0 ^ (row & 7)) * 8)) = c0;
            *(uint4*)(dst + (((ch0 + 1) ^ (row & 7)) * 8)) = c1;
        }
    }
    {
        const float* Wm[3] = {Wq, Wk, Wv};
        #pragma unroll
        for (int it = 0; it < 6; ++it) {
            const int mat = it >> 1;
            const int e = (it & 1) * 32 + (tid >> 3), ch = tid & 7;
            const float* p = Wm[mat] + h * DH_ * DH_ + e * DH_ + ch * 8;
            float4 a = *(const float4*)(p);
            float4 c = *(const float4*)(p + 4);
            uint4 u;
            u.x = rnepk(a.x, a.y); u.y = rnepk(a.z, a.w);
            u.z = rnepk(c.x, c.y); u.w = rnepk(c.z, c.w);
            *(uint4*)(&wl[mat][e * 64 + ((ch ^ (e & 7)) * 8)]) = u;
        }
    }
    __syncthreads();

    const int srow = w * 32 + l31;
    bf16x8 xf[4];
    #pragma unroll
    for (int st = 0; st < 4; ++st)
        xf[st] = *(const bf16x8*)(xs + srow * 64 + (((st * 2 + l5) ^ (srow & 7)) * 8));

    ushort* mybnc = &bnc[w][0];

    #pragma unroll
    for (int mat = 0; mat < 2; ++mat) {
        const float* bias = mat ? bk : bq;
        f32x16 acc[2];
        #pragma unroll
        for (int et = 0; et < 2; ++et) {
            acc[et] = zero16();
            const int e = et * 32 + l31;
            #pragma unroll
            for (int st = 0; st < 4; ++st) {
                bf16x8 wf = *(const bf16x8*)(&wl[mat][e * 64 + (((st * 2 + l5) ^ (e & 7)) * 8)]);
                acc[et] = __builtin_amdgcn_mfma_f32_32x32x16_bf16(wf, xf[st], acc[et], 0, 0, 0);
            }
        }
        #pragma unroll
        for (int et = 0; et < 2; ++et)
            #pragma unroll
            for (int rg = 0; rg < 4; ++rg) {
                float4 b4 = *(const float4*)(bias + h * DH_ + et * 32 + rg * 8 + l5 * 4);
                float v0 = acc[et][rg * 4 + 0] + b4.x;
                float v1 = acc[et][rg * 4 + 1] + b4.y;
                float v2 = acc[et][rg * 4 + 2] + b4.z;
                float v3 = acc[et][rg * 4 + 3] + b4.w;
                if (mat == 0) { v0 *= SCALE; v1 *= SCALE; v2 *= SCALE; v3 *= SCALE; }
                uint2 pk;
                pk.x = rnepk(v0, v1); pk.y = rnepk(v2, v3);
                *(uint2*)(mybnc + l31 * 72 + et * 32 + rg * 8 + l5 * 4) = pk;
            }
        ushort* Og = mat ? Kb : Qb;
        #pragma unroll
        for (int i = 0; i < 4; ++i) {
            const int slot = lane + 64 * i;
            const int r = slot >> 3, c = slot & 7;
            uint4 v = *(const uint4*)(mybnc + r * 72 + c * 8);
            *(uint4*)(Og + ((size_t)(bh * S_ + s0 + w * 32 + r)) * DH_ + c * 8) = v;
        }
    }

    {
        f32x16 acc[2];
        #pragma unroll
        for (int et = 0; et < 2; ++et) {
            acc[et] = zero16();
            const int e = et * 32 + l31;
            #pragma unroll
            for (int st = 0; st < 4; ++st) {
                bf16x8 wf = *(const bf16x8*)(&wl[2][e * 64 + (((st * 2 + l5) ^ (e & 7)) * 8)]);
                acc[et] = __builtin_amdgcn_mfma_f32_32x32x16_bf16(xf[st], wf, acc[et], 0, 0, 0);
            }
        }
        const float bvv0 = bv[h * DH_ + l31], bvv1 = bv[h * DH_ + 32 + l31];
        #pragma unroll
        for (int et = 0; et < 2; ++et) {
            const float bb = et ? bvv1 : bvv0;
            #pragma unroll
            for (int rg = 0; rg < 4; ++rg) {
                uint2 pk;
                pk.x = rnepk(acc[et][rg * 4 + 0] + bb, acc[et][rg * 4 + 1] + bb);
                pk.y = rnepk(acc[et][rg * 4 + 2] + bb, acc[et][rg * 4 + 3] + bb);
                *(uint2*)(mybnc + (et * 32 + l31) * 40 + rg * 8 + l5 * 4) = pk;
            }
        }
        #pragma unroll
        for (int i = 0; i < 4; ++i) {
            const int slot = lane + 64 * i;
            const int r = slot >> 2, c = slot & 3;
            uint4 v = *(const uint4*)(mybnc + r * 40 + c * 8);
            *(uint4*)(Vtg + ((size_t)(bh * DH_ + r)) * S_ + s0 + w * 32 + c * 8) = v;
        }
    }
}

// ---------------------------------------------------------------------------
// Kernel 2: flash attention, 32x32x16 MFMA, 32 q-rows/wave.
// grid = 512 blocks (bh = blk&31: all 16 q-blocks of a bh land on one XCD,
// K/V L2-resident), 4 waves/block -> 2 blocks/CU, 8 waves/CU (the R4 failure
// was 1 wave/SIMD). Single-buffered K/V + register prefetch, 2 barriers/kt.
// P per-wave stride 68 ushorts (136 B: bank phase 2*l31 -> 2-way, free),
// accessed b64-only. Epilogue overlays all of LDS for coalesced stores.
// ---------------------------------------------------------------------------
__global__ __launch_bounds__(256, 2)
void flash_mfma(const ushort* __restrict__ Qb, const ushort* __restrict__ Kb,
                const ushort* __restrict__ Vtg, float* __restrict__ out)
{
    const int blk = blockIdx.x;
    const int bh = blk & 31, qblk = blk >> 5;
    const int b = bh >> 3, h = bh & 7;
    const int tid = threadIdx.x;
    const int w = tid >> 6, lane = tid & 63, l31 = lane & 31, l5 = lane >> 5;

    // [0,8K): Ks | [8K,16K): Vs | [16K,33.9K): P; epilogue overlays all 34816 B
    __shared__ __align__(16) ushort lds_u[17408];
    ushort* Ks = lds_u;                                // [key][dh] xor-swizzled
    ushort* Vs = lds_u + 4096;                         // [dh][key] xor-swizzled
    ushort* Pw = lds_u + 8192 + w * (32 * 68);         // [q][key] stride 68

    // ---- Q B-frags (held all kernel): q = q0 + l31 ----
    const int q0 = qblk * 128 + w * 32;
    bf16x8 qf[4];
    #pragma unroll
    for (int st = 0; st < 4; ++st)
        qf[st] = *(const bf16x8*)(Qb + ((size_t)(bh * S_ + q0 + l31)) * DH_
                                  + st * 16 + l5 * 8);

    f32x16 O[2];                       // O^T [dht]: lane col = q = l31
    O[0] = zero16(); O[1] = zero16();
    float lsum = 0.f;

    const ushort* kg = Kb + (size_t)bh * S_ * DH_;
    const ushort* vg = Vtg + (size_t)bh * DH_ * S_;
    const int sr0 = tid >> 3, sc = tid & 7, sr1 = sr0 + 32;

    // ---- prologue: stage kt=0 ----
    uint4 kv0 = *(const uint4*)(kg + (size_t)sr0 * DH_ + sc * 8);
    uint4 kv1 = *(const uint4*)(kg + (size_t)sr1 * DH_ + sc * 8);
    uint4 vv0 = *(const uint4*)(vg + (size_t)sr0 * S_ + sc * 8);
    uint4 vv1 = *(const uint4*)(vg + (size_t)sr1 * S_ + sc * 8);
    *(uint4*)(Ks + sr0 * 64 + ((sc ^ (sr0 & 7)) * 8)) = kv0;
    *(uint4*)(Ks + sr1 * 64 + ((sc ^ (sr1 & 7)) * 8)) = kv1;
    *(uint4*)(Vs + sr0 * 64 + ((sc ^ (sr0 & 7)) * 8)) = vv0;
    *(uint4*)(Vs + sr1 * 64 + ((sc ^ (sr1 & 7)) * 8)) = vv1;

    for (int kt = 0; kt < 32; ++kt) {
        __syncthreads();                      // staging of tile kt visible
        if (kt < 31) {                        // prefetch kt+1 into registers
            const size_t ko = (size_t)(kt + 1) * 64 * DH_;
            const int vo = (kt + 1) * 64;
            kv0 = *(const uint4*)(kg + ko + (size_t)sr0 * DH_ + sc * 8);
            kv1 = *(const uint4*)(kg + ko + (size_t)sr1 * DH_ + sc * 8);
            vv0 = *(const uint4*)(vg + (size_t)sr0 * S_ + vo + sc * 8);
            vv1 = *(const uint4*)(vg + (size_t)sr1 * S_ + vo + sc * 8);
        }

        // ---- S^T = K·Q^T per key-half g; C: lane col = q, rows = keys ----
        #pragma unroll
        for (int g = 0; g < 2; ++g) {
            const int key = g * 32 + l31;
            bf16x8 kf[4];
            #pragma unroll
            for (int st = 0; st < 4; ++st)
                kf[st] = *(const bf16x8*)(Ks + key * 64 + (((st * 2 + l5) ^ (key & 7)) * 8));
            f32x16 sc_ = zero16();
            #pragma unroll
            for (int st = 0; st < 4; ++st)
                sc_ = __builtin_amdgcn_mfma_f32_32x32x16_bf16(kf[st], qf[st], sc_, 0, 0, 0);
            #pragma unroll
            for (int rg = 0; rg < 4; ++rg) {
                float p0 = __builtin_amdgcn_exp2f(sc_[rg * 4 + 0]);
                float p1 = __builtin_amdgcn_exp2f(sc_[rg * 4 + 1]);
                float p2 = __builtin_amdgcn_exp2f(sc_[rg * 4 + 2]);
                float p3 = __builtin_amdgcn_exp2f(sc_[rg * 4 + 3]);
                lsum += (p0 + p1) + (p2 + p3);
                uint2 pk;
                pk.x = truncpk(p0, p1); pk.y = truncpk(p2, p3);
                // P[q = l31][key = g*32 + rg*8 + l5*4 + {0..3}]
                *(uint2*)(Pw + l31 * 68 + g * 32 + rg * 8 + l5 * 4) = pk;
            }
        }

        // ---- PV: O^T[dht] += Vt·P^T. B = P^T[k=key][n=q]: lane n = l31 ----
        bf16x8 pf[4];
        #pragma unroll
        for (int st = 0; st < 4; ++st) {
            const ushort* pp = Pw + l31 * 68 + st * 16 + l5 * 8;
            uint2 lo = *(const uint2*)(pp);
            uint2 hi = *(const uint2*)(pp + 4);
            u32x4 t; t.x = lo.x; t.y = lo.y; t.z = hi.x; t.w = hi.y;
            pf[st] = __builtin_bit_cast(bf16x8, t);
        }
        #pragma unroll
        for (int dht = 0; dht < 2; ++dht) {
            const int dh = dht * 32 + l31;
            bf16x8 vf[4];
            #pragma unroll
            for (int st = 0; st < 4; ++st)
                vf[st] = *(const bf16x8*)(Vs + dh * 64 + (((st * 2 + l5) ^ (dh & 7)) * 8));
            #pragma unroll
            for (int st = 0; st < 4; ++st)
                O[dht] = __builtin_amdgcn_mfma_f32_32x32x16_bf16(vf[st], pf[st], O[dht], 0, 0, 0);
        }

        __syncthreads();                      // all waves done reading tile kt
        if (kt < 31) {
            *(uint4*)(Ks + sr0 * 64 + ((sc ^ (sr0 & 7)) * 8)) = kv0;
            *(uint4*)(Ks + sr1 * 64 + ((sc ^ (sr1 & 7)) * 8)) = kv1;
            *(uint4*)(Vs + sr0 * 64 + ((sc ^ (sr0 & 7)) * 8)) = vv0;
            *(uint4*)(Vs + sr1 * 64 + ((sc ^ (sr1 & 7)) * 8)) = vv1;
        }
    }

    // ---- finalize: q = l31's l split across l5 halves ----
    lsum += __shfl_xor(lsum, 32);
    const float linv = 1.0f / lsum;
    #pragma unroll
    for (int dht = 0; dht < 2; ++dht)
        #pragma unroll
        for (int i = 0; i < 16; ++i) O[dht][i] *= linv;

    __syncthreads();                          // overlay LDS with O bounce
    float* ob = (float*)lds_u + w * (32 * 68);   // per-wave [32 q][68] fp32
    #pragma unroll
    for (int dht = 0; dht < 2; ++dht)
        #pragma unroll
        for (int rg = 0; rg < 4; ++rg) {
            f32x4 v4;
            v4[0] = O[dht][rg * 4 + 0];
            v4[1] = O[dht][rg * 4 + 1];
            v4[2] = O[dht][rg * 4 + 2];
            v4[3] = O[dht][rg * 4 + 3];
            *(f32x4*)(ob + l31 * 68 + dht * 32 + rg * 8 + l5 * 4) = v4;
        }
    #pragma unroll
    for (int i = 0; i < 8; ++i) {             // 32 rows x 16 chunks of 16 B
        const int slot = lane + 64 * i;
        const int r = slot >> 4, c = slot & 15;
        f32x4 v = *(const f32x4*)(ob + r * 68 + c * 4);
        *(f32x4*)(out + ((size_t)(b * S_ + q0 + r)) * D_ + h * DH_ + c * 4) = v;
    }
}

extern "C" void kernel_launch(void* const* d_in, const int* in_sizes, int n_in,
                              void* d_out, int out_size, void* d_ws, size_t ws_size,
                              hipStream_t stream) {
    const float* x  = (const float*)d_in[0];
    const float* Wq = (const float*)d_in[1];
    const float* bq = (const float*)d_in[2];
    const float* Wk = (const float*)d_in[3];
    const float* bk = (const float*)d_in[4];
    const float* Wv = (const float*)d_in[5];
    const float* bv = (const float*)d_in[6];
    float* outp = (float*)d_out;

    ushort* Qb  = (ushort*)d_ws;                       // [BH][S][DH] bf16, 8 MB
    ushort* Kb  = Qb + (size_t)BH_ * S_ * DH_;         // 8 MB
    ushort* Vtg = Kb + (size_t)BH_ * S_ * DH_;         // [BH][DH][S] bf16, 8 MB

    qkv_mfma<<<dim3(BH_, S_ / 128), 256, 0, stream>>>(x, Wq, bq, Wk, bk, Wv, bv,
                                                      Qb, Kb, Vtg);
    flash_mfma<<<dim3(32 * 16), 256, 0, stream>>>(Qb, Kb, Vtg, outp);
}